// Round 1
// baseline (1861.046 us; speedup 1.0000x reference)
//
#include <hip/hip_runtime.h>
#include <stdint.h>

#define DIM 3072
#define HEADS 24
#define HD 128
#define RANKN 64
#define CONDN 1024
#define BLK 2048
#define SEQN 3072
#define NIPN 64

typedef __attribute__((ext_vector_type(8))) short s8v;
typedef __attribute__((ext_vector_type(4))) float fx4;

static __device__ __forceinline__ unsigned short f2bf(float f){
  union{float f; unsigned u;} v; v.f=f;
  unsigned r = v.u + 0x7FFFu + ((v.u>>16)&1u);
  return (unsigned short)(r>>16);
}

#define GL16(g,l) __builtin_amdgcn_global_load_lds((const __attribute__((address_space(1))) void*)(g), (__attribute__((address_space(3))) void*)(l), 16, 0, 0)
#define MFMA(a,b,c) __builtin_amdgcn_mfma_f32_16x16x32_bf16((a),(b),(c),0,0,0)

// ---------------- fp32 -> bf16 convert (4 elems/thread) ----------------
__global__ __launch_bounds__(256) void cvt_f32_bf16(const float* __restrict__ src,
                                                    unsigned short* __restrict__ dst, int n4){
  int i = blockIdx.x*256 + threadIdx.x;
  if (i < n4){
    float4 v = ((const float4*)src)[i];
    ushort4 o;
    o.x = f2bf(v.x); o.y = f2bf(v.y); o.z = f2bf(v.z); o.w = f2bf(v.w);
    ((ushort4*)dst)[i] = o;
  }
}

// ---------------- bf16 GEMM: C[M][N] = A[M][K] * B[N][K]^T (+bias) ----------------
// tile 128x128, BK=64, 4 waves, global_load_lds staging, row&7 XOR LDS swizzle
#define BM 128
#define BN 128
#define BK 64
__global__ __launch_bounds__(256) void gemm_bf16(const unsigned short* __restrict__ A,
                                                 const unsigned short* __restrict__ B,
                                                 float* __restrict__ C,
                                                 const float* __restrict__ bias,
                                                 int M){
  const int K = DIM, N = DIM;
  __shared__ unsigned short As[BM*BK];
  __shared__ unsigned short Bs[BN*BK];
  int tid = threadIdx.x;
  int lane = tid & 63, w = tid >> 6;
  int l15 = lane & 15, l16 = lane >> 4;
  int m0 = blockIdx.y * BM, n0 = blockIdx.x * BN;
  int wr = (w >> 1) * 64, wc = (w & 1) * 64;

  fx4 acc[4][4] = {};

  for (int kt = 0; kt < K; kt += BK){
    #pragma unroll
    for (int i = 0; i < 4; i++){
      int p = i*256 + tid;
      int row = p >> 3, cc = p & 7;
      int gc = cc ^ (row & 7);
      int arow = m0 + row; if (arow > M-1) arow = M-1;
      GL16(A + (size_t)arow*K + kt + gc*8, As + p*8);
      GL16(B + (size_t)(n0+row)*K + kt + gc*8, Bs + p*8);
    }
    __syncthreads();
    #pragma unroll
    for (int kk = 0; kk < 2; kk++){
      s8v af[4], bfr[4];
      #pragma unroll
      for (int t = 0; t < 4; t++){
        int rowa = wr + t*16 + l15;
        int ca = (kk*4 + l16) ^ (rowa & 7);
        af[t] = *(const s8v*)(As + rowa*BK + ca*8);
        int rowb = wc + t*16 + l15;
        int cb = (kk*4 + l16) ^ (rowb & 7);
        bfr[t] = *(const s8v*)(Bs + rowb*BK + cb*8);
      }
      #pragma unroll
      for (int mt = 0; mt < 4; mt++)
        #pragma unroll
        for (int nt = 0; nt < 4; nt++)
          acc[mt][nt] = MFMA(af[mt], bfr[nt], acc[mt][nt]);
    }
    __syncthreads();
  }
  #pragma unroll
  for (int mt = 0; mt < 4; mt++){
    #pragma unroll
    for (int j = 0; j < 4; j++){
      int row = m0 + wr + mt*16 + l16*4 + j;
      if (row < M){
        #pragma unroll
        for (int nt = 0; nt < 4; nt++){
          int col = n0 + wc + nt*16 + l15;
          float v = acc[mt][nt][j];
          if (bias) v += bias[col];
          C[(size_t)row*N + col] = v;
        }
      }
    }
  }
}

// ---------------- LoRA down: out[3][1024][64] ----------------
__global__ __launch_bounds__(256) void lora_down(const float* __restrict__ hs,
                                                 const float* __restrict__ dq,
                                                 const float* __restrict__ dk,
                                                 const float* __restrict__ dv,
                                                 float* __restrict__ out){
  __shared__ float xs[DIM];
  __shared__ float part[256];
  int z = blockIdx.y, r = blockIdx.x, tid = threadIdx.x;
  const float* dw = (z==0)?dq:((z==1)?dk:dv);
  const float* row = hs + (size_t)(BLK + r)*DIM;
  for (int i = tid; i < DIM; i += 256) xs[i] = row[i];
  __syncthreads();
  int col = tid & 63, seg = tid >> 6;
  const float* wrow = dw + (size_t)col*DIM + seg*768;
  const float* xseg = xs + seg*768;
  float a = 0.f;
  #pragma unroll 8
  for (int k = 0; k < 768; k++) a += xseg[k]*wrow[k];
  part[tid] = a;
  __syncthreads();
  if (tid < 64){
    float v = part[tid] + part[tid+64] + part[tid+128] + part[tid+192];
    out[((size_t)z*CONDN + r)*64 + tid] = v;
  }
}

// ---------------- LoRA up: add into q/k/v rows [2048, 3072) ----------------
__global__ __launch_bounds__(256) void lora_up(const float* __restrict__ down,
                                               const float* __restrict__ uq,
                                               const float* __restrict__ uk,
                                               const float* __restrict__ uv,
                                               float* __restrict__ q,
                                               float* __restrict__ k,
                                               float* __restrict__ v){
  __shared__ float dsv[64];
  int z = blockIdx.y, r = blockIdx.x, tid = threadIdx.x;
  const float* up = (z==0)?uq:((z==1)?uk:uv);
  float* dst = ((z==0)?q:((z==1)?k:v)) + (size_t)(BLK + r)*DIM;
  if (tid < 64) dsv[tid] = down[((size_t)z*CONDN + r)*64 + tid];
  __syncthreads();
  #pragma unroll
  for (int i = 0; i < 12; i++){
    int col = i*256 + tid;
    const float* ur = up + (size_t)col*64;
    float a = 0.f;
    #pragma unroll
    for (int t = 0; t < 64; t++) a += dsv[t]*ur[t];
    dst[col] += a;
  }
}

// ---------------- rmsnorm + rope -> bf16 head-major [H][S][HD] ----------------
__global__ __launch_bounds__(256) void norm_rope(const float* __restrict__ src,
                                                 unsigned short* __restrict__ dst,
                                                 const float* __restrict__ wt,
                                                 const float* __restrict__ rc,
                                                 const float* __restrict__ rs,
                                                 int S){
  int tid = threadIdx.x, lane = tid & 63, w = tid >> 6;
  int r = blockIdx.x*4 + w;
  int pos = r % S, h = r / S;
  const float* x = src + (size_t)pos*DIM + h*HD;
  float2 xv = *(const float2*)(x + 2*lane);
  float ss = xv.x*xv.x + xv.y*xv.y;
  #pragma unroll
  for (int o = 1; o < 64; o <<= 1) ss += __shfl_xor(ss, o);
  float rr = rsqrtf(ss*(1.f/128.f) + 1e-6f);
  float y0 = xv.x*rr*wt[2*lane], y1 = xv.y*rr*wt[2*lane+1];
  float2 cv = *(const float2*)(rc + (size_t)pos*HD + 2*lane);
  float2 sv = *(const float2*)(rs + (size_t)pos*HD + 2*lane);
  float o0 = y0*cv.x - y1*sv.x;
  float o1 = y1*cv.y + y0*sv.y;
  ushort2 ov; ov.x = f2bf(o0); ov.y = f2bf(o1);
  *(ushort2*)(dst + ((size_t)h*S + pos)*HD + 2*lane) = ov;
}

// ---------------- ip_k rmsnorm (eps 1e-5, no weight), layout preserved ----------------
__global__ __launch_bounds__(256) void ipk_norm(const float* __restrict__ src,
                                                float* __restrict__ dst){
  int tid = threadIdx.x, lane = tid & 63, w = tid >> 6;
  int r = blockIdx.x*4 + w;         // r < 64*24
  int pos = r / HEADS, h = r % HEADS;
  const float* x = src + (size_t)pos*DIM + h*HD;
  float2 xv = *(const float2*)(x + 2*lane);
  float ss = xv.x*xv.x + xv.y*xv.y;
  #pragma unroll
  for (int o = 1; o < 64; o <<= 1) ss += __shfl_xor(ss, o);
  float rr = rsqrtf(ss*(1.f/128.f) + 1e-5f);
  float* d = dst + (size_t)pos*DIM + h*HD;
  *(float2*)(d + 2*lane) = make_float2(xv.x*rr, xv.y*rr);
}

// ---------------- v -> Vt bf16 [H][HD][SEQ] transpose ----------------
__global__ __launch_bounds__(256) void v_transpose(const float* __restrict__ v,
                                                   unsigned short* __restrict__ Vt){
  __shared__ float t[64][129];
  int h = blockIdx.y, p0 = blockIdx.x*64, tid = threadIdx.x;
  int dcol = tid & 127, prow2 = tid >> 7;
  #pragma unroll
  for (int i = 0; i < 32; i++){
    int pos = i*2 + prow2;
    t[pos][dcol] = v[(size_t)(p0+pos)*DIM + h*HD + dcol];
  }
  __syncthreads();
  int pos = tid & 63, dbase = tid >> 6;
  #pragma unroll
  for (int i = 0; i < 32; i++){
    int d = i*4 + dbase;
    Vt[((size_t)h*HD + d)*SEQN + p0 + pos] = f2bf(t[pos][d]);
  }
}

// ---------------- ip attention (64 keys, fp32 vector), writes d_out ----------------
__global__ __launch_bounds__(256) void ip_attn(const float* __restrict__ q,
                                               const float* __restrict__ ipk,
                                               const float* __restrict__ ipv,
                                               float* __restrict__ out){
  __shared__ float qs[4][HD];
  __shared__ float ps[4][64];
  int tid = threadIdx.x, lane = tid & 63, w = tid >> 6;
  int r = blockIdx.x*4 + w;         // r < 24*2048
  int h = r >> 11, pos = r & 2047;
  float2 qv = *(const float2*)(q + (size_t)pos*DIM + h*HD + 2*lane);
  qs[w][2*lane] = qv.x; qs[w][2*lane+1] = qv.y;
  asm volatile("s_waitcnt lgkmcnt(0)" ::: "memory");
  const float* kr = ipk + (size_t)lane*DIM + h*HD;
  float s = 0.f;
  #pragma unroll
  for (int d = 0; d < HD; d += 4){
    float4 kv4 = *(const float4*)(kr + d);
    s += qs[w][d]*kv4.x + qs[w][d+1]*kv4.y + qs[w][d+2]*kv4.z + qs[w][d+3]*kv4.w;
  }
  s *= 0.08838834764831845f;
  float mx = s;
  #pragma unroll
  for (int o = 1; o < 64; o <<= 1) mx = fmaxf(mx, __shfl_xor(mx, o));
  float p = __expf(s - mx);
  float sum = p;
  #pragma unroll
  for (int o = 1; o < 64; o <<= 1) sum += __shfl_xor(sum, o);
  ps[w][lane] = p / sum;
  asm volatile("s_waitcnt lgkmcnt(0)" ::: "memory");
  float a0 = 0.f, a1 = 0.f;
  #pragma unroll 8
  for (int k2 = 0; k2 < 64; k2++){
    float pk = ps[w][k2];
    float2 vv = *(const float2*)(ipv + (size_t)k2*DIM + h*HD + 2*lane);
    a0 += pk*vv.x; a1 += pk*vv.y;
  }
  float* op = out + (size_t)pos*DIM + h*HD + 2*lane;
  *(float2*)op = make_float2(a0, a1);
}

// ---------------- main flash attention: 2048 q rows x 3072 keys, no mask ----------------
#define QB 64
#define KVB 64
__global__ __launch_bounds__(256) void flash_attn(const unsigned short* __restrict__ Qn,
                                                  const unsigned short* __restrict__ Kn,
                                                  const unsigned short* __restrict__ Vt,
                                                  float* __restrict__ out){
  __shared__ unsigned short Ks[KVB*HD];
  __shared__ unsigned short Vs[HD*KVB];
  __shared__ unsigned short Ps[4][16*KVB];
  int tid = threadIdx.x, lane = tid & 63, w = tid >> 6;
  int l15 = lane & 15, l16 = lane >> 4;
  int h = blockIdx.y;
  int q0 = blockIdx.x*QB + w*16;
  const unsigned short* Qh = Qn + (size_t)h*BLK*HD;
  const unsigned short* Kh = Kn + (size_t)h*SEQN*HD;
  const unsigned short* Vh = Vt + (size_t)h*HD*SEQN;

  s8v qf[4];
  #pragma unroll
  for (int kf = 0; kf < 4; kf++)
    qf[kf] = *(const s8v*)(Qh + (size_t)(q0 + l15)*HD + kf*32 + l16*8);

  fx4 o[8] = {};
  float mrow[4], lrow[4];
  #pragma unroll
  for (int j = 0; j < 4; j++){ mrow[j] = -1e30f; lrow[j] = 0.f; }

  for (int kv0 = 0; kv0 < SEQN; kv0 += KVB){
    #pragma unroll
    for (int i = 0; i < 4; i++){
      int p = i*256 + tid;
      int row = p >> 4, cc = p & 15;
      int gc = cc ^ (row & 7);
      GL16(Kh + (size_t)(kv0+row)*HD + gc*8, Ks + p*8);
    }
    #pragma unroll
    for (int i = 0; i < 4; i++){
      int p = i*256 + tid;
      int row = p >> 3, cc = p & 7;
      int gc = cc ^ (row & 7);
      GL16(Vh + (size_t)row*SEQN + kv0 + gc*8, Vs + p*8);
    }
    __syncthreads();

    fx4 s[4] = {};
    #pragma unroll
    for (int ct = 0; ct < 4; ct++){
      #pragma unroll
      for (int kk = 0; kk < 4; kk++){
        int row = ct*16 + l15;
        int c = (kk*4 + l16) ^ (row & 7);
        s8v b = *(const s8v*)(Ks + row*HD + c*8);
        s[ct] = MFMA(qf[kk], b, s[ct]);
      }
    }
    const float SC = 0.08838834764831845f;
    #pragma unroll
    for (int ct = 0; ct < 4; ct++)
      #pragma unroll
      for (int j = 0; j < 4; j++) s[ct][j] *= SC;

    float mnew[4], alpha[4], rssum[4];
    #pragma unroll
    for (int j = 0; j < 4; j++){
      float v = fmaxf(fmaxf(s[0][j], s[1][j]), fmaxf(s[2][j], s[3][j]));
      #pragma unroll
      for (int o2 = 1; o2 < 16; o2 <<= 1) v = fmaxf(v, __shfl_xor(v, o2));
      mnew[j] = fmaxf(mrow[j], v);
      alpha[j] = __expf(mrow[j] - mnew[j]);
      mrow[j] = mnew[j];
      rssum[j] = 0.f;
    }
    #pragma unroll
    for (int ct = 0; ct < 4; ct++)
      #pragma unroll
      for (int j = 0; j < 4; j++){
        float p = __expf(s[ct][j] - mnew[j]);
        s[ct][j] = p;
        rssum[j] += p;
      }
    #pragma unroll
    for (int j = 0; j < 4; j++){
      #pragma unroll
      for (int o2 = 1; o2 < 16; o2 <<= 1) rssum[j] += __shfl_xor(rssum[j], o2);
      lrow[j] = lrow[j]*alpha[j] + rssum[j];
    }
    #pragma unroll
    for (int nt = 0; nt < 8; nt++)
      #pragma unroll
      for (int j = 0; j < 4; j++) o[nt][j] *= alpha[j];

    // write P to per-wave swizzled LDS
    #pragma unroll
    for (int ct = 0; ct < 4; ct++)
      #pragma unroll
      for (int j = 0; j < 4; j++){
        int row = l16*4 + j;
        int cidx = ct*16 + l15;
        Ps[w][row*64 + (((cidx>>3) ^ (row&7))<<3) + (cidx&7)] = f2bf(s[ct][j]);
      }
    asm volatile("s_waitcnt lgkmcnt(0)" ::: "memory");
    s8v pa[2];
    #pragma unroll
    for (int kk = 0; kk < 2; kk++){
      int c = (kk*4 + l16) ^ (l15 & 7);
      pa[kk] = *(const s8v*)(&Ps[w][l15*64 + c*8]);
    }
    #pragma unroll
    for (int nt = 0; nt < 8; nt++){
      #pragma unroll
      for (int kk = 0; kk < 2; kk++){
        int row = nt*16 + l15;
        int c = (kk*4 + l16) ^ (row & 7);
        s8v bv = *(const s8v*)(Vs + row*KVB + c*8);
        o[nt] = MFMA(pa[kk], bv, o[nt]);
      }
    }
    __syncthreads();
  }
  #pragma unroll
  for (int nt = 0; nt < 8; nt++)
    #pragma unroll
    for (int j = 0; j < 4; j++){
      int row = q0 + l16*4 + j;
      int d = nt*16 + l15;
      float v = o[nt][j] / lrow[j];
      float* p = out + (size_t)row*DIM + h*HD + d;
      *p += v;
    }
}

extern "C" void kernel_launch(void* const* d_in, const int* in_sizes, int n_in,
                              void* d_out, int out_size, void* d_ws, size_t ws_size,
                              hipStream_t stream){
  (void)in_sizes; (void)n_in; (void)out_size;
  const float* hs       = (const float*)d_in[0];
  const float* image_emb= (const float*)d_in[1];
  const float* rope_cos = (const float*)d_in[2];
  const float* rope_sin = (const float*)d_in[3];
  const float* wq = (const float*)d_in[4];
  const float* bq = (const float*)d_in[5];
  const float* wk = (const float*)d_in[6];
  const float* bk = (const float*)d_in[7];
  const float* wv = (const float*)d_in[8];
  const float* bv = (const float*)d_in[9];
  const float* norm_q_w = (const float*)d_in[10];
  const float* norm_k_w = (const float*)d_in[11];
  const float* q_down = (const float*)d_in[12];
  const float* q_up   = (const float*)d_in[13];
  const float* k_down = (const float*)d_in[14];
  const float* k_up   = (const float*)d_in[15];
  const float* v_down = (const float*)d_in[16];
  const float* v_up   = (const float*)d_in[17];
  const float* wk_ip  = (const float*)d_in[18];
  const float* wv_ip  = (const float*)d_in[19];
  float* out = (float*)d_out;

  char* ws = (char*)d_ws;
  size_t off = 0;
  auto alloc = [&](size_t bytes){ void* p = ws + off; off += (bytes + 255) & ~(size_t)255; return p; };
  unsigned short* hs_bf = (unsigned short*)alloc((size_t)SEQN*DIM*2);
  unsigned short* w_bf  = (unsigned short*)alloc((size_t)DIM*DIM*2);
  unsigned short* ie_bf = (unsigned short*)alloc((size_t)NIPN*DIM*2);
  float* qb = (float*)alloc((size_t)SEQN*DIM*4);
  float* kb = (float*)alloc((size_t)SEQN*DIM*4);
  float* vb = (float*)alloc((size_t)SEQN*DIM*4);
  float* ipk_pre = (float*)alloc((size_t)NIPN*DIM*4);
  float* ipv_pre = (float*)alloc((size_t)NIPN*DIM*4);
  float* ipk_n   = (float*)alloc((size_t)NIPN*DIM*4);
  float* downb   = (float*)alloc((size_t)3*CONDN*64*4);
  unsigned short* Qn = (unsigned short*)alloc((size_t)HEADS*BLK*HD*2);
  unsigned short* Kn = (unsigned short*)alloc((size_t)HEADS*SEQN*HD*2);
  unsigned short* Vt = (unsigned short*)alloc((size_t)HEADS*HD*SEQN*2);
  if (off > ws_size) return;  // workspace too small -> leave output poisoned (visible failure)

  int n4;
  n4 = SEQN*DIM/4;
  cvt_f32_bf16<<<(n4+255)/256, 256, 0, stream>>>(hs, hs_bf, n4);
  n4 = NIPN*DIM/4;
  cvt_f32_bf16<<<(n4+255)/256, 256, 0, stream>>>(image_emb, ie_bf, n4);

  dim3 gfull(DIM/BN, SEQN/BM);
  dim3 gip(DIM/BN, 1);
  n4 = DIM*DIM/4;
  cvt_f32_bf16<<<(n4+255)/256, 256, 0, stream>>>(wq, w_bf, n4);
  gemm_bf16<<<gfull, 256, 0, stream>>>(hs_bf, w_bf, qb, bq, SEQN);
  cvt_f32_bf16<<<(n4+255)/256, 256, 0, stream>>>(wk, w_bf, n4);
  gemm_bf16<<<gfull, 256, 0, stream>>>(hs_bf, w_bf, kb, bk, SEQN);
  cvt_f32_bf16<<<(n4+255)/256, 256, 0, stream>>>(wv, w_bf, n4);
  gemm_bf16<<<gfull, 256, 0, stream>>>(hs_bf, w_bf, vb, bv, SEQN);
  cvt_f32_bf16<<<(n4+255)/256, 256, 0, stream>>>(wk_ip, w_bf, n4);
  gemm_bf16<<<gip, 256, 0, stream>>>(ie_bf, w_bf, ipk_pre, nullptr, NIPN);
  cvt_f32_bf16<<<(n4+255)/256, 256, 0, stream>>>(wv_ip, w_bf, n4);
  gemm_bf16<<<gip, 256, 0, stream>>>(ie_bf, w_bf, ipv_pre, nullptr, NIPN);

  lora_down<<<dim3(CONDN,3), 256, 0, stream>>>(hs, q_down, k_down, v_down, downb);
  lora_up<<<dim3(CONDN,3), 256, 0, stream>>>(downb, q_up, k_up, v_up, qb, kb, vb);

  ipk_norm<<<(NIPN*HEADS)/4, 256, 0, stream>>>(ipk_pre, ipk_n);
  norm_rope<<<(BLK*HEADS)/4, 256, 0, stream>>>(qb, Qn, norm_q_w, rope_cos, rope_sin, BLK);
  norm_rope<<<(SEQN*HEADS)/4, 256, 0, stream>>>(kb, Kn, norm_k_w, rope_cos, rope_sin, SEQN);
  v_transpose<<<dim3(SEQN/64, HEADS), 256, 0, stream>>>(vb, Vt);

  ip_attn<<<(HEADS*BLK)/4, 256, 0, stream>>>(qb, ipk_n, ipv_pre, out);
  flash_attn<<<dim3(BLK/QB, HEADS), 256, 0, stream>>>(Qn, Kn, Vt, out);
}

// Round 2
// 1143.003 us; speedup vs baseline: 1.6282x; 1.6282x over previous
//
#include <hip/hip_runtime.h>
#include <stdint.h>

#define DIM 3072
#define HEADS 24
#define HD 128
#define RANKN 64
#define CONDN 1024
#define BLK 2048
#define SEQN 3072
#define NIPN 64

typedef __attribute__((ext_vector_type(8))) short s8v;
typedef __attribute__((ext_vector_type(4))) float fx4;

static __device__ __forceinline__ unsigned short f2bf(float f){
  union{float f; unsigned u;} v; v.f=f;
  unsigned r = v.u + 0x7FFFu + ((v.u>>16)&1u);
  return (unsigned short)(r>>16);
}

#define GL16(g,l) __builtin_amdgcn_global_load_lds((const __attribute__((address_space(1))) void*)(g), (__attribute__((address_space(3))) void*)(l), 16, 0, 0)
#define MFMA(a,b,c) __builtin_amdgcn_mfma_f32_16x16x32_bf16((a),(b),(c),0,0,0)

// ---------------- fp32 -> bf16 convert (4 elems/thread) ----------------
__global__ __launch_bounds__(256) void cvt_f32_bf16(const float* __restrict__ src,
                                                    unsigned short* __restrict__ dst, int n4){
  int i = blockIdx.x*256 + threadIdx.x;
  if (i < n4){
    float4 v = ((const float4*)src)[i];
    ushort4 o;
    o.x = f2bf(v.x); o.y = f2bf(v.y); o.z = f2bf(v.z); o.w = f2bf(v.w);
    ((ushort4*)dst)[i] = o;
  }
}

// ---------------- bf16 GEMM: C[M][N] = A[M][K] * B[N][K]^T (+bias) ----------------
#define BM 128
#define BN 128
#define BK 64
__global__ __launch_bounds__(256) void gemm_bf16(const unsigned short* __restrict__ A,
                                                 const unsigned short* __restrict__ B,
                                                 float* __restrict__ C,
                                                 const float* __restrict__ bias,
                                                 int M){
  const int K = DIM, N = DIM;
  __shared__ unsigned short As[BM*BK];
  __shared__ unsigned short Bs[BN*BK];
  int tid = threadIdx.x;
  int lane = tid & 63, w = tid >> 6;
  int l15 = lane & 15, l16 = lane >> 4;
  int m0 = blockIdx.y * BM, n0 = blockIdx.x * BN;
  int wr = (w >> 1) * 64, wc = (w & 1) * 64;

  fx4 acc[4][4] = {};

  for (int kt = 0; kt < K; kt += BK){
    #pragma unroll
    for (int i = 0; i < 4; i++){
      int p = i*256 + tid;
      int row = p >> 3, cc = p & 7;
      int gc = cc ^ (row & 7);
      int arow = m0 + row; if (arow > M-1) arow = M-1;
      GL16(A + (size_t)arow*K + kt + gc*8, As + p*8);
      GL16(B + (size_t)(n0+row)*K + kt + gc*8, Bs + p*8);
    }
    __syncthreads();
    #pragma unroll
    for (int kk = 0; kk < 2; kk++){
      s8v af[4], bfr[4];
      #pragma unroll
      for (int t = 0; t < 4; t++){
        int rowa = wr + t*16 + l15;
        int ca = (kk*4 + l16) ^ (rowa & 7);
        af[t] = *(const s8v*)(As + rowa*BK + ca*8);
        int rowb = wc + t*16 + l15;
        int cb = (kk*4 + l16) ^ (rowb & 7);
        bfr[t] = *(const s8v*)(Bs + rowb*BK + cb*8);
      }
      #pragma unroll
      for (int mt = 0; mt < 4; mt++)
        #pragma unroll
        for (int nt = 0; nt < 4; nt++)
          acc[mt][nt] = MFMA(af[mt], bfr[nt], acc[mt][nt]);
    }
    __syncthreads();
  }
  #pragma unroll
  for (int mt = 0; mt < 4; mt++){
    #pragma unroll
    for (int j = 0; j < 4; j++){
      int row = m0 + wr + mt*16 + l16*4 + j;
      if (row < M){
        #pragma unroll
        for (int nt = 0; nt < 4; nt++){
          int col = n0 + wc + nt*16 + l15;
          float v = acc[mt][nt][j];
          if (bias) v += bias[col];
          C[(size_t)row*N + col] = v;
        }
      }
    }
  }
}

// ---------------- LoRA down (MFMA): downb[z][1024][64] = hs_bf[2048:] @ downW^T ----------------
// grid (1, 8, 3), block 256. BM=128, BN=64, BK=64.
__global__ __launch_bounds__(256) void lora_down_g(const unsigned short* __restrict__ A,
                                                   const unsigned short* __restrict__ D0,
                                                   const unsigned short* __restrict__ D1,
                                                   const unsigned short* __restrict__ D2,
                                                   unsigned short* __restrict__ outb){
  __shared__ unsigned short As[128*64];
  __shared__ unsigned short Bs[64*64];
  int tid = threadIdx.x, lane = tid & 63, w = tid >> 6;
  int l15 = lane & 15, l16 = lane >> 4;
  int z = blockIdx.z;
  int m0 = blockIdx.y * 128;
  const unsigned short* Dw = (z==0)?D0:((z==1)?D1:D2);
  int wr = w * 32;
  fx4 acc[2][4] = {};
  for (int kt = 0; kt < DIM; kt += 64){
    #pragma unroll
    for (int i = 0; i < 4; i++){
      int p = i*256 + tid;
      int row = p >> 3, cc = p & 7;
      int gc = cc ^ (row & 7);
      GL16(A + (size_t)(m0+row)*DIM + kt + gc*8, As + p*8);
    }
    #pragma unroll
    for (int i = 0; i < 2; i++){
      int p = i*256 + tid;
      int row = p >> 3, cc = p & 7;
      int gc = cc ^ (row & 7);
      GL16(Dw + (size_t)row*DIM + kt + gc*8, Bs + p*8);
    }
    __syncthreads();
    #pragma unroll
    for (int kk = 0; kk < 2; kk++){
      s8v af[2], bfr[4];
      #pragma unroll
      for (int t = 0; t < 2; t++){
        int rowa = wr + t*16 + l15;
        int ca = (kk*4 + l16) ^ (rowa & 7);
        af[t] = *(const s8v*)(As + rowa*64 + ca*8);
      }
      #pragma unroll
      for (int t = 0; t < 4; t++){
        int rowb = t*16 + l15;
        int cb = (kk*4 + l16) ^ (rowb & 7);
        bfr[t] = *(const s8v*)(Bs + rowb*64 + cb*8);
      }
      #pragma unroll
      for (int mt = 0; mt < 2; mt++)
        #pragma unroll
        for (int nt = 0; nt < 4; nt++)
          acc[mt][nt] = MFMA(af[mt], bfr[nt], acc[mt][nt]);
    }
    __syncthreads();
  }
  #pragma unroll
  for (int mt = 0; mt < 2; mt++)
    #pragma unroll
    for (int j = 0; j < 4; j++){
      int row = m0 + wr + mt*16 + l16*4 + j;
      #pragma unroll
      for (int nt = 0; nt < 4; nt++){
        int col = nt*16 + l15;
        outb[((size_t)z*CONDN + row)*64 + col] = f2bf(acc[mt][nt][j]);
      }
    }
}

// ---------------- LoRA up (MFMA): q/k/v rows [2048:3072) += downb @ upW^T ----------------
// grid (24, 8, 3), block 256. 128x128 tile, single K=64 step.
__global__ __launch_bounds__(256) void lora_up_g(const unsigned short* __restrict__ downb,
                                                 const unsigned short* __restrict__ U0,
                                                 const unsigned short* __restrict__ U1,
                                                 const unsigned short* __restrict__ U2,
                                                 float* __restrict__ q,
                                                 float* __restrict__ k,
                                                 float* __restrict__ v){
  __shared__ unsigned short As[128*64];
  __shared__ unsigned short Bs[128*64];
  int tid = threadIdx.x, lane = tid & 63, w = tid >> 6;
  int l15 = lane & 15, l16 = lane >> 4;
  int z = blockIdx.z;
  int m0 = blockIdx.y * 128, n0 = blockIdx.x * 128;
  const unsigned short* A = downb + (size_t)z*CONDN*64;
  const unsigned short* B = (z==0)?U0:((z==1)?U1:U2);
  float* dst = ((z==0)?q:((z==1)?k:v)) + (size_t)BLK*DIM;
  int wr = (w >> 1) * 64, wc = (w & 1) * 64;
  fx4 acc[4][4] = {};
  #pragma unroll
  for (int i = 0; i < 4; i++){
    int p = i*256 + tid;
    int row = p >> 3, cc = p & 7;
    int gc = cc ^ (row & 7);
    GL16(A + (size_t)(m0+row)*64 + gc*8, As + p*8);
    GL16(B + (size_t)(n0+row)*64 + gc*8, Bs + p*8);
  }
  __syncthreads();
  #pragma unroll
  for (int kk = 0; kk < 2; kk++){
    s8v af[4], bfr[4];
    #pragma unroll
    for (int t = 0; t < 4; t++){
      int rowa = wr + t*16 + l15;
      int ca = (kk*4 + l16) ^ (rowa & 7);
      af[t] = *(const s8v*)(As + rowa*64 + ca*8);
      int rowb = wc + t*16 + l15;
      int cb = (kk*4 + l16) ^ (rowb & 7);
      bfr[t] = *(const s8v*)(Bs + rowb*64 + cb*8);
    }
    #pragma unroll
    for (int mt = 0; mt < 4; mt++)
      #pragma unroll
      for (int nt = 0; nt < 4; nt++)
        acc[mt][nt] = MFMA(af[mt], bfr[nt], acc[mt][nt]);
  }
  #pragma unroll
  for (int mt = 0; mt < 4; mt++)
    #pragma unroll
    for (int j = 0; j < 4; j++){
      int row = m0 + wr + mt*16 + l16*4 + j;
      float* drow = dst + (size_t)row*DIM;
      #pragma unroll
      for (int nt = 0; nt < 4; nt++){
        int col = n0 + wc + nt*16 + l15;
        drow[col] += acc[mt][nt][j];
      }
    }
}

// ---------------- rmsnorm + rope -> bf16 head-major [H][S][HD] ----------------
__global__ __launch_bounds__(256) void norm_rope(const float* __restrict__ src,
                                                 unsigned short* __restrict__ dst,
                                                 const float* __restrict__ wt,
                                                 const float* __restrict__ rc,
                                                 const float* __restrict__ rs,
                                                 int S){
  int tid = threadIdx.x, lane = tid & 63, w = tid >> 6;
  int r = blockIdx.x*4 + w;
  int pos = r % S, h = r / S;
  const float* x = src + (size_t)pos*DIM + h*HD;
  float2 xv = *(const float2*)(x + 2*lane);
  float ss = xv.x*xv.x + xv.y*xv.y;
  #pragma unroll
  for (int o = 1; o < 64; o <<= 1) ss += __shfl_xor(ss, o);
  float rr = rsqrtf(ss*(1.f/128.f) + 1e-6f);
  float y0 = xv.x*rr*wt[2*lane], y1 = xv.y*rr*wt[2*lane+1];
  float2 cv = *(const float2*)(rc + (size_t)pos*HD + 2*lane);
  float2 sv = *(const float2*)(rs + (size_t)pos*HD + 2*lane);
  float o0 = y0*cv.x - y1*sv.x;
  float o1 = y1*cv.y + y0*sv.y;
  ushort2 ov; ov.x = f2bf(o0); ov.y = f2bf(o1);
  *(ushort2*)(dst + ((size_t)h*S + pos)*HD + 2*lane) = ov;
}

// ---------------- ip_k rmsnorm (eps 1e-5, no weight), layout preserved ----------------
__global__ __launch_bounds__(256) void ipk_norm(const float* __restrict__ src,
                                                float* __restrict__ dst){
  int tid = threadIdx.x, lane = tid & 63, w = tid >> 6;
  int r = blockIdx.x*4 + w;         // r < 64*24
  int pos = r / HEADS, h = r % HEADS;
  const float* x = src + (size_t)pos*DIM + h*HD;
  float2 xv = *(const float2*)(x + 2*lane);
  float ss = xv.x*xv.x + xv.y*xv.y;
  #pragma unroll
  for (int o = 1; o < 64; o <<= 1) ss += __shfl_xor(ss, o);
  float rr = rsqrtf(ss*(1.f/128.f) + 1e-5f);
  float* d = dst + (size_t)pos*DIM + h*HD;
  *(float2*)(d + 2*lane) = make_float2(xv.x*rr, xv.y*rr);
}

// ---------------- v -> Vt bf16 [H][HD][SEQ] transpose ----------------
__global__ __launch_bounds__(256) void v_transpose(const float* __restrict__ v,
                                                   unsigned short* __restrict__ Vt){
  __shared__ float t[64][129];
  int h = blockIdx.y, p0 = blockIdx.x*64, tid = threadIdx.x;
  int dcol = tid & 127, prow2 = tid >> 7;
  #pragma unroll
  for (int i = 0; i < 32; i++){
    int pos = i*2 + prow2;
    t[pos][dcol] = v[(size_t)(p0+pos)*DIM + h*HD + dcol];
  }
  __syncthreads();
  int pos = tid & 63, dbase = tid >> 6;
  #pragma unroll
  for (int i = 0; i < 32; i++){
    int d = i*4 + dbase;
    Vt[((size_t)h*HD + d)*SEQN + p0 + pos] = f2bf(t[pos][d]);
  }
}

// ---------------- ip attention (64 keys, fp32 vector), writes d_out ----------------
__global__ __launch_bounds__(256) void ip_attn(const float* __restrict__ q,
                                               const float* __restrict__ ipk,
                                               const float* __restrict__ ipv,
                                               float* __restrict__ out){
  __shared__ float qs[4][HD];
  __shared__ float ps[4][64];
  int tid = threadIdx.x, lane = tid & 63, w = tid >> 6;
  int r = blockIdx.x*4 + w;         // r < 24*2048
  int h = r >> 11, pos = r & 2047;
  float2 qv = *(const float2*)(q + (size_t)pos*DIM + h*HD + 2*lane);
  qs[w][2*lane] = qv.x; qs[w][2*lane+1] = qv.y;
  asm volatile("s_waitcnt lgkmcnt(0)" ::: "memory");
  const float* kr = ipk + (size_t)lane*DIM + h*HD;
  float s = 0.f;
  #pragma unroll
  for (int d = 0; d < HD; d += 4){
    float4 kv4 = *(const float4*)(kr + d);
    s += qs[w][d]*kv4.x + qs[w][d+1]*kv4.y + qs[w][d+2]*kv4.z + qs[w][d+3]*kv4.w;
  }
  s *= 0.08838834764831845f;
  float mx = s;
  #pragma unroll
  for (int o = 1; o < 64; o <<= 1) mx = fmaxf(mx, __shfl_xor(mx, o));
  float p = __expf(s - mx);
  float sum = p;
  #pragma unroll
  for (int o = 1; o < 64; o <<= 1) sum += __shfl_xor(sum, o);
  ps[w][lane] = p / sum;
  asm volatile("s_waitcnt lgkmcnt(0)" ::: "memory");
  float a0 = 0.f, a1 = 0.f;
  #pragma unroll 8
  for (int k2 = 0; k2 < 64; k2++){
    float pk = ps[w][k2];
    float2 vv = *(const float2*)(ipv + (size_t)k2*DIM + h*HD + 2*lane);
    a0 += pk*vv.x; a1 += pk*vv.y;
  }
  float* op = out + (size_t)pos*DIM + h*HD + 2*lane;
  *(float2*)op = make_float2(a0, a1);
}

// ---------------- main flash attention: 2048 q rows x 3072 keys, no mask ----------------
#define QB 64
#define KVB 64
__global__ __launch_bounds__(256) void flash_attn(const unsigned short* __restrict__ Qn,
                                                  const unsigned short* __restrict__ Kn,
                                                  const unsigned short* __restrict__ Vt,
                                                  float* __restrict__ out){
  __shared__ unsigned short Ks[KVB*HD];
  __shared__ unsigned short Vs[HD*KVB];
  __shared__ unsigned short Ps[4][16*KVB];
  int tid = threadIdx.x, lane = tid & 63, w = tid >> 6;
  int l15 = lane & 15, l16 = lane >> 4;
  int h = blockIdx.y;
  int q0 = blockIdx.x*QB + w*16;
  const unsigned short* Qh = Qn + (size_t)h*BLK*HD;
  const unsigned short* Kh = Kn + (size_t)h*SEQN*HD;
  const unsigned short* Vh = Vt + (size_t)h*HD*SEQN;

  s8v qf[4];
  #pragma unroll
  for (int kf = 0; kf < 4; kf++)
    qf[kf] = *(const s8v*)(Qh + (size_t)(q0 + l15)*HD + kf*32 + l16*8);

  fx4 o[8] = {};
  float mrow[4], lrow[4];
  #pragma unroll
  for (int j = 0; j < 4; j++){ mrow[j] = -1e30f; lrow[j] = 0.f; }

  for (int kv0 = 0; kv0 < SEQN; kv0 += KVB){
    #pragma unroll
    for (int i = 0; i < 4; i++){
      int p = i*256 + tid;
      int row = p >> 4, cc = p & 15;
      int gc = cc ^ (row & 7);
      GL16(Kh + (size_t)(kv0+row)*HD + gc*8, Ks + p*8);
    }
    #pragma unroll
    for (int i = 0; i < 4; i++){
      int p = i*256 + tid;
      int row = p >> 3, cc = p & 7;
      int gc = cc ^ (row & 7);
      GL16(Vh + (size_t)row*SEQN + kv0 + gc*8, Vs + p*8);
    }
    __syncthreads();

    fx4 s[4] = {};
    #pragma unroll
    for (int ct = 0; ct < 4; ct++){
      #pragma unroll
      for (int kk = 0; kk < 4; kk++){
        int row = ct*16 + l15;
        int c = (kk*4 + l16) ^ (row & 7);
        s8v b = *(const s8v*)(Ks + row*HD + c*8);
        s[ct] = MFMA(qf[kk], b, s[ct]);
      }
    }
    const float SC = 0.08838834764831845f;
    #pragma unroll
    for (int ct = 0; ct < 4; ct++)
      #pragma unroll
      for (int j = 0; j < 4; j++) s[ct][j] *= SC;

    float mnew[4], alpha[4], rssum[4];
    #pragma unroll
    for (int j = 0; j < 4; j++){
      float v = fmaxf(fmaxf(s[0][j], s[1][j]), fmaxf(s[2][j], s[3][j]));
      #pragma unroll
      for (int o2 = 1; o2 < 16; o2 <<= 1) v = fmaxf(v, __shfl_xor(v, o2));
      mnew[j] = fmaxf(mrow[j], v);
      alpha[j] = __expf(mrow[j] - mnew[j]);
      mrow[j] = mnew[j];
      rssum[j] = 0.f;
    }
    #pragma unroll
    for (int ct = 0; ct < 4; ct++)
      #pragma unroll
      for (int j = 0; j < 4; j++){
        float p = __expf(s[ct][j] - mnew[j]);
        s[ct][j] = p;
        rssum[j] += p;
      }
    #pragma unroll
    for (int j = 0; j < 4; j++){
      #pragma unroll
      for (int o2 = 1; o2 < 16; o2 <<= 1) rssum[j] += __shfl_xor(rssum[j], o2);
      lrow[j] = lrow[j]*alpha[j] + rssum[j];
    }
    #pragma unroll
    for (int nt = 0; nt < 8; nt++)
      #pragma unroll
      for (int j = 0; j < 4; j++) o[nt][j] *= alpha[j];

    // write P to per-wave swizzled LDS
    #pragma unroll
    for (int ct = 0; ct < 4; ct++)
      #pragma unroll
      for (int j = 0; j < 4; j++){
        int row = l16*4 + j;
        int cidx = ct*16 + l15;
        Ps[w][row*64 + (((cidx>>3) ^ (row&7))<<3) + (cidx&7)] = f2bf(s[ct][j]);
      }
    asm volatile("s_waitcnt lgkmcnt(0)" ::: "memory");
    s8v pa[2];
    #pragma unroll
    for (int kk = 0; kk < 2; kk++){
      int c = (kk*4 + l16) ^ (l15 & 7);
      pa[kk] = *(const s8v*)(&Ps[w][l15*64 + c*8]);
    }
    #pragma unroll
    for (int nt = 0; nt < 8; nt++){
      #pragma unroll
      for (int kk = 0; kk < 2; kk++){
        int row = nt*16 + l15;
        int c = (kk*4 + l16) ^ (row & 7);
        s8v bv = *(const s8v*)(Vs + row*KVB + c*8);
        o[nt] = MFMA(pa[kk], bv, o[nt]);
      }
    }
    __syncthreads();
  }
  #pragma unroll
  for (int nt = 0; nt < 8; nt++)
    #pragma unroll
    for (int j = 0; j < 4; j++){
      int row = q0 + l16*4 + j;
      int d = nt*16 + l15;
      float v = o[nt][j] / lrow[j];
      float* p = out + (size_t)row*DIM + h*HD + d;
      *p += v;
    }
}

extern "C" void kernel_launch(void* const* d_in, const int* in_sizes, int n_in,
                              void* d_out, int out_size, void* d_ws, size_t ws_size,
                              hipStream_t stream){
  (void)in_sizes; (void)n_in; (void)out_size;
  const float* hs       = (const float*)d_in[0];
  const float* image_emb= (const float*)d_in[1];
  const float* rope_cos = (const float*)d_in[2];
  const float* rope_sin = (const float*)d_in[3];
  const float* wq = (const float*)d_in[4];
  const float* bq = (const float*)d_in[5];
  const float* wk = (const float*)d_in[6];
  const float* bk = (const float*)d_in[7];
  const float* wv = (const float*)d_in[8];
  const float* bv = (const float*)d_in[9];
  const float* norm_q_w = (const float*)d_in[10];
  const float* norm_k_w = (const float*)d_in[11];
  const float* q_down = (const float*)d_in[12];
  const float* q_up   = (const float*)d_in[13];
  const float* k_down = (const float*)d_in[14];
  const float* k_up   = (const float*)d_in[15];
  const float* v_down = (const float*)d_in[16];
  const float* v_up   = (const float*)d_in[17];
  const float* wk_ip  = (const float*)d_in[18];
  const float* wv_ip  = (const float*)d_in[19];
  float* out = (float*)d_out;

  char* ws = (char*)d_ws;
  size_t off = 0;
  auto alloc = [&](size_t bytes){ void* p = ws + off; off += (bytes + 255) & ~(size_t)255; return p; };
  unsigned short* hs_bf = (unsigned short*)alloc((size_t)SEQN*DIM*2);
  unsigned short* w_bf  = (unsigned short*)alloc((size_t)DIM*DIM*2);
  unsigned short* ie_bf = (unsigned short*)alloc((size_t)NIPN*DIM*2);
  float* qb = (float*)alloc((size_t)SEQN*DIM*4);
  float* kb = (float*)alloc((size_t)SEQN*DIM*4);
  float* vb = (float*)alloc((size_t)SEQN*DIM*4);
  float* ipk_pre = (float*)alloc((size_t)NIPN*DIM*4);
  float* ipv_pre = (float*)alloc((size_t)NIPN*DIM*4);
  float* ipk_n   = (float*)alloc((size_t)NIPN*DIM*4);
  unsigned short* dwn_bf[3];
  unsigned short* upw_bf[3];
  for (int i = 0; i < 3; i++) dwn_bf[i] = (unsigned short*)alloc((size_t)RANKN*DIM*2);
  for (int i = 0; i < 3; i++) upw_bf[i] = (unsigned short*)alloc((size_t)DIM*RANKN*2);
  unsigned short* downb_bf = (unsigned short*)alloc((size_t)3*CONDN*RANKN*2);
  unsigned short* Qn = (unsigned short*)alloc((size_t)HEADS*BLK*HD*2);
  unsigned short* Kn = (unsigned short*)alloc((size_t)HEADS*SEQN*HD*2);
  unsigned short* Vt = (unsigned short*)alloc((size_t)HEADS*HD*SEQN*2);
  if (off > ws_size) return;  // workspace too small -> leave output poisoned (visible failure)

  int n4;
  n4 = SEQN*DIM/4;
  cvt_f32_bf16<<<(n4+255)/256, 256, 0, stream>>>(hs, hs_bf, n4);
  n4 = NIPN*DIM/4;
  cvt_f32_bf16<<<(n4+255)/256, 256, 0, stream>>>(image_emb, ie_bf, n4);

  dim3 gfull(DIM/BN, SEQN/BM);
  dim3 gip(DIM/BN, 1);
  n4 = DIM*DIM/4;
  cvt_f32_bf16<<<(n4+255)/256, 256, 0, stream>>>(wq, w_bf, n4);
  gemm_bf16<<<gfull, 256, 0, stream>>>(hs_bf, w_bf, qb, bq, SEQN);
  cvt_f32_bf16<<<(n4+255)/256, 256, 0, stream>>>(wk, w_bf, n4);
  gemm_bf16<<<gfull, 256, 0, stream>>>(hs_bf, w_bf, kb, bk, SEQN);
  cvt_f32_bf16<<<(n4+255)/256, 256, 0, stream>>>(wv, w_bf, n4);
  gemm_bf16<<<gfull, 256, 0, stream>>>(hs_bf, w_bf, vb, bv, SEQN);
  cvt_f32_bf16<<<(n4+255)/256, 256, 0, stream>>>(wk_ip, w_bf, n4);
  gemm_bf16<<<gip, 256, 0, stream>>>(ie_bf, w_bf, ipk_pre, nullptr, NIPN);
  cvt_f32_bf16<<<(n4+255)/256, 256, 0, stream>>>(wv_ip, w_bf, n4);
  gemm_bf16<<<gip, 256, 0, stream>>>(ie_bf, w_bf, ipv_pre, nullptr, NIPN);

  // LoRA path (MFMA)
  n4 = RANKN*DIM/4;
  cvt_f32_bf16<<<(n4+255)/256, 256, 0, stream>>>(q_down, dwn_bf[0], n4);
  cvt_f32_bf16<<<(n4+255)/256, 256, 0, stream>>>(k_down, dwn_bf[1], n4);
  cvt_f32_bf16<<<(n4+255)/256, 256, 0, stream>>>(v_down, dwn_bf[2], n4);
  cvt_f32_bf16<<<(n4+255)/256, 256, 0, stream>>>(q_up, upw_bf[0], n4);
  cvt_f32_bf16<<<(n4+255)/256, 256, 0, stream>>>(k_up, upw_bf[1], n4);
  cvt_f32_bf16<<<(n4+255)/256, 256, 0, stream>>>(v_up, upw_bf[2], n4);
  lora_down_g<<<dim3(1, CONDN/128, 3), 256, 0, stream>>>(hs_bf + (size_t)BLK*DIM,
      dwn_bf[0], dwn_bf[1], dwn_bf[2], downb_bf);
  lora_up_g<<<dim3(DIM/128, CONDN/128, 3), 256, 0, stream>>>(downb_bf,
      upw_bf[0], upw_bf[1], upw_bf[2], qb, kb, vb);

  ipk_norm<<<(NIPN*HEADS)/4, 256, 0, stream>>>(ipk_pre, ipk_n);
  norm_rope<<<(BLK*HEADS)/4, 256, 0, stream>>>(qb, Qn, norm_q_w, rope_cos, rope_sin, BLK);
  norm_rope<<<(SEQN*HEADS)/4, 256, 0, stream>>>(kb, Kn, norm_k_w, rope_cos, rope_sin, SEQN);
  v_transpose<<<dim3(SEQN/64, HEADS), 256, 0, stream>>>(vb, Vt);

  ip_attn<<<(HEADS*BLK)/4, 256, 0, stream>>>(qb, ipk_n, ipv_pre, out);
  flash_attn<<<dim3(BLK/QB, HEADS), 256, 0, stream>>>(Qn, Kn, Vt, out);
}

// Round 3
// 903.056 us; speedup vs baseline: 2.0608x; 1.2657x over previous
//
#include <hip/hip_runtime.h>
#include <stdint.h>

#define DIM 3072
#define HEADS 24
#define HD 128
#define RANKN 64
#define CONDN 1024
#define BLK 2048
#define SEQN 3072
#define NIPN 64

typedef __attribute__((ext_vector_type(8))) short s8v;
typedef __attribute__((ext_vector_type(4))) float fx4;

static __device__ __forceinline__ unsigned short f2bf(float f){
  union{float f; unsigned u;} v; v.f=f;
  unsigned r = v.u + 0x7FFFu + ((v.u>>16)&1u);
  return (unsigned short)(r>>16);
}

#define GL16(g,l) __builtin_amdgcn_global_load_lds((const __attribute__((address_space(1))) void*)(g), (__attribute__((address_space(3))) void*)(l), 16, 0, 0)
#define MFMA(a,b,c) __builtin_amdgcn_mfma_f32_16x16x32_bf16((a),(b),(c),0,0,0)

// ---------------- fp32 -> bf16 convert (4 elems/thread) ----------------
__global__ __launch_bounds__(256) void cvt_f32_bf16(const float* __restrict__ src,
                                                    unsigned short* __restrict__ dst, int n4){
  int i = blockIdx.x*256 + threadIdx.x;
  if (i < n4){
    float4 v = ((const float4*)src)[i];
    ushort4 o;
    o.x = f2bf(v.x); o.y = f2bf(v.y); o.z = f2bf(v.z); o.w = f2bf(v.w);
    ((ushort4*)dst)[i] = o;
  }
}

// ---------------- bf16 GEMM: C[M][N] = A[M][K] * B[N][K]^T (+bias) ----------------
#define BM 128
#define BN 128
#define BK 64
__global__ __launch_bounds__(256) void gemm_bf16(const unsigned short* __restrict__ A,
                                                 const unsigned short* __restrict__ B,
                                                 float* __restrict__ C,
                                                 const float* __restrict__ bias,
                                                 int M){
  const int K = DIM, N = DIM;
  __shared__ unsigned short As[BM*BK];
  __shared__ unsigned short Bs[BN*BK];
  int tid = threadIdx.x;
  int lane = tid & 63, w = tid >> 6;
  int l15 = lane & 15, l16 = lane >> 4;
  int m0 = blockIdx.y * BM, n0 = blockIdx.x * BN;
  int wr = (w >> 1) * 64, wc = (w & 1) * 64;

  fx4 acc[4][4] = {};

  for (int kt = 0; kt < K; kt += BK){
    #pragma unroll
    for (int i = 0; i < 4; i++){
      int p = i*256 + tid;
      int row = p >> 3, cc = p & 7;
      int gc = cc ^ (row & 7);
      int arow = m0 + row; if (arow > M-1) arow = M-1;
      GL16(A + (size_t)arow*K + kt + gc*8, As + p*8);
      GL16(B + (size_t)(n0+row)*K + kt + gc*8, Bs + p*8);
    }
    __syncthreads();
    #pragma unroll
    for (int kk = 0; kk < 2; kk++){
      s8v af[4], bfr[4];
      #pragma unroll
      for (int t = 0; t < 4; t++){
        int rowa = wr + t*16 + l15;
        int ca = (kk*4 + l16) ^ (rowa & 7);
        af[t] = *(const s8v*)(As + rowa*BK + ca*8);
        int rowb = wc + t*16 + l15;
        int cb = (kk*4 + l16) ^ (rowb & 7);
        bfr[t] = *(const s8v*)(Bs + rowb*BK + cb*8);
      }
      #pragma unroll
      for (int mt = 0; mt < 4; mt++)
        #pragma unroll
        for (int nt = 0; nt < 4; nt++)
          acc[mt][nt] = MFMA(af[mt], bfr[nt], acc[mt][nt]);
    }
    __syncthreads();
  }
  #pragma unroll
  for (int mt = 0; mt < 4; mt++){
    #pragma unroll
    for (int j = 0; j < 4; j++){
      int row = m0 + wr + mt*16 + l16*4 + j;
      if (row < M){
        #pragma unroll
        for (int nt = 0; nt < 4; nt++){
          int col = n0 + wc + nt*16 + l15;
          float v = acc[mt][nt][j];
          if (bias) v += bias[col];
          C[(size_t)row*N + col] = v;
        }
      }
    }
  }
}

// ---------------- LoRA down (MFMA): downb[z][1024][64] = hs_bf[2048:] @ downW^T ----------------
__global__ __launch_bounds__(256) void lora_down_g(const unsigned short* __restrict__ A,
                                                   const unsigned short* __restrict__ D0,
                                                   const unsigned short* __restrict__ D1,
                                                   const unsigned short* __restrict__ D2,
                                                   unsigned short* __restrict__ outb){
  __shared__ unsigned short As[128*64];
  __shared__ unsigned short Bs[64*64];
  int tid = threadIdx.x, lane = tid & 63, w = tid >> 6;
  int l15 = lane & 15, l16 = lane >> 4;
  int z = blockIdx.z;
  int m0 = blockIdx.y * 128;
  const unsigned short* Dw = (z==0)?D0:((z==1)?D1:D2);
  int wr = w * 32;
  fx4 acc[2][4] = {};
  for (int kt = 0; kt < DIM; kt += 64){
    #pragma unroll
    for (int i = 0; i < 4; i++){
      int p = i*256 + tid;
      int row = p >> 3, cc = p & 7;
      int gc = cc ^ (row & 7);
      GL16(A + (size_t)(m0+row)*DIM + kt + gc*8, As + p*8);
    }
    #pragma unroll
    for (int i = 0; i < 2; i++){
      int p = i*256 + tid;
      int row = p >> 3, cc = p & 7;
      int gc = cc ^ (row & 7);
      GL16(Dw + (size_t)row*DIM + kt + gc*8, Bs + p*8);
    }
    __syncthreads();
    #pragma unroll
    for (int kk = 0; kk < 2; kk++){
      s8v af[2], bfr[4];
      #pragma unroll
      for (int t = 0; t < 2; t++){
        int rowa = wr + t*16 + l15;
        int ca = (kk*4 + l16) ^ (rowa & 7);
        af[t] = *(const s8v*)(As + rowa*64 + ca*8);
      }
      #pragma unroll
      for (int t = 0; t < 4; t++){
        int rowb = t*16 + l15;
        int cb = (kk*4 + l16) ^ (rowb & 7);
        bfr[t] = *(const s8v*)(Bs + rowb*64 + cb*8);
      }
      #pragma unroll
      for (int mt = 0; mt < 2; mt++)
        #pragma unroll
        for (int nt = 0; nt < 4; nt++)
          acc[mt][nt] = MFMA(af[mt], bfr[nt], acc[mt][nt]);
    }
    __syncthreads();
  }
  #pragma unroll
  for (int mt = 0; mt < 2; mt++)
    #pragma unroll
    for (int j = 0; j < 4; j++){
      int row = m0 + wr + mt*16 + l16*4 + j;
      #pragma unroll
      for (int nt = 0; nt < 4; nt++){
        int col = nt*16 + l15;
        outb[((size_t)z*CONDN + row)*64 + col] = f2bf(acc[mt][nt][j]);
      }
    }
}

// ---------------- LoRA up (MFMA): q/k/v rows [2048:3072) += downb @ upW^T ----------------
__global__ __launch_bounds__(256) void lora_up_g(const unsigned short* __restrict__ downb,
                                                 const unsigned short* __restrict__ U0,
                                                 const unsigned short* __restrict__ U1,
                                                 const unsigned short* __restrict__ U2,
                                                 float* __restrict__ q,
                                                 float* __restrict__ k,
                                                 float* __restrict__ v){
  __shared__ unsigned short As[128*64];
  __shared__ unsigned short Bs[128*64];
  int tid = threadIdx.x, lane = tid & 63, w = tid >> 6;
  int l15 = lane & 15, l16 = lane >> 4;
  int z = blockIdx.z;
  int m0 = blockIdx.y * 128, n0 = blockIdx.x * 128;
  const unsigned short* A = downb + (size_t)z*CONDN*64;
  const unsigned short* B = (z==0)?U0:((z==1)?U1:U2);
  float* dst = ((z==0)?q:((z==1)?k:v)) + (size_t)BLK*DIM;
  int wr = (w >> 1) * 64, wc = (w & 1) * 64;
  fx4 acc[4][4] = {};
  #pragma unroll
  for (int i = 0; i < 4; i++){
    int p = i*256 + tid;
    int row = p >> 3, cc = p & 7;
    int gc = cc ^ (row & 7);
    GL16(A + (size_t)(m0+row)*64 + gc*8, As + p*8);
    GL16(B + (size_t)(n0+row)*64 + gc*8, Bs + p*8);
  }
  __syncthreads();
  #pragma unroll
  for (int kk = 0; kk < 2; kk++){
    s8v af[4], bfr[4];
    #pragma unroll
    for (int t = 0; t < 4; t++){
      int rowa = wr + t*16 + l15;
      int ca = (kk*4 + l16) ^ (rowa & 7);
      af[t] = *(const s8v*)(As + rowa*64 + ca*8);
      int rowb = wc + t*16 + l15;
      int cb = (kk*4 + l16) ^ (rowb & 7);
      bfr[t] = *(const s8v*)(Bs + rowb*64 + cb*8);
    }
    #pragma unroll
    for (int mt = 0; mt < 4; mt++)
      #pragma unroll
      for (int nt = 0; nt < 4; nt++)
        acc[mt][nt] = MFMA(af[mt], bfr[nt], acc[mt][nt]);
  }
  #pragma unroll
  for (int mt = 0; mt < 4; mt++)
    #pragma unroll
    for (int j = 0; j < 4; j++){
      int row = m0 + wr + mt*16 + l16*4 + j;
      float* drow = dst + (size_t)row*DIM;
      #pragma unroll
      for (int nt = 0; nt < 4; nt++){
        int col = n0 + wc + nt*16 + l15;
        drow[col] += acc[mt][nt][j];
      }
    }
}

// ---------------- rmsnorm + rope -> bf16 head-major [H][S][HD] ----------------
__global__ __launch_bounds__(256) void norm_rope(const float* __restrict__ src,
                                                 unsigned short* __restrict__ dst,
                                                 const float* __restrict__ wt,
                                                 const float* __restrict__ rc,
                                                 const float* __restrict__ rs,
                                                 int S){
  int tid = threadIdx.x, lane = tid & 63, w = tid >> 6;
  int r = blockIdx.x*4 + w;
  int pos = r % S, h = r / S;
  const float* x = src + (size_t)pos*DIM + h*HD;
  float2 xv = *(const float2*)(x + 2*lane);
  float ss = xv.x*xv.x + xv.y*xv.y;
  #pragma unroll
  for (int o = 1; o < 64; o <<= 1) ss += __shfl_xor(ss, o);
  float rr = rsqrtf(ss*(1.f/128.f) + 1e-6f);
  float y0 = xv.x*rr*wt[2*lane], y1 = xv.y*rr*wt[2*lane+1];
  float2 cv = *(const float2*)(rc + (size_t)pos*HD + 2*lane);
  float2 sv = *(const float2*)(rs + (size_t)pos*HD + 2*lane);
  float o0 = y0*cv.x - y1*sv.x;
  float o1 = y1*cv.y + y0*sv.y;
  ushort2 ov; ov.x = f2bf(o0); ov.y = f2bf(o1);
  *(ushort2*)(dst + ((size_t)h*S + pos)*HD + 2*lane) = ov;
}

// ---------------- ip_k rmsnorm (eps 1e-5, no weight) -> bf16 [H][64][HD] ----------------
__global__ __launch_bounds__(256) void ipk_norm_bf(const float* __restrict__ src,
                                                   unsigned short* __restrict__ dst){
  int tid = threadIdx.x, lane = tid & 63, w = tid >> 6;
  int r = blockIdx.x*4 + w;         // r < 64*24
  int pos = r / HEADS, h = r % HEADS;
  const float* x = src + (size_t)pos*DIM + h*HD;
  float2 xv = *(const float2*)(x + 2*lane);
  float ss = xv.x*xv.x + xv.y*xv.y;
  #pragma unroll
  for (int o = 1; o < 64; o <<= 1) ss += __shfl_xor(ss, o);
  float rr = rsqrtf(ss*(1.f/128.f) + 1e-5f);
  ushort2 ov; ov.x = f2bf(xv.x*rr); ov.y = f2bf(xv.y*rr);
  *(ushort2*)(dst + ((size_t)h*NIPN + pos)*HD + 2*lane) = ov;
}

// ---------------- ipv -> bf16 [H][HD][64] transpose ----------------
__global__ __launch_bounds__(256) void ipv_transpose(const float* __restrict__ ipv,
                                                     unsigned short* __restrict__ vt){
  int h = blockIdx.x, tid = threadIdx.x;
  #pragma unroll
  for (int i = 0; i < 32; i++){
    int idx = i*256 + tid;       // idx = d*64 + key
    int d = idx >> 6, key = idx & 63;
    vt[((size_t)h*HD + d)*64 + key] = f2bf(ipv[(size_t)key*DIM + h*HD + d]);
  }
}

// ---------------- v -> Vt bf16 [H][HD][SEQ] transpose ----------------
__global__ __launch_bounds__(256) void v_transpose(const float* __restrict__ v,
                                                   unsigned short* __restrict__ Vt){
  __shared__ float t[64][129];
  int h = blockIdx.y, p0 = blockIdx.x*64, tid = threadIdx.x;
  int dcol = tid & 127, prow2 = tid >> 7;
  #pragma unroll
  for (int i = 0; i < 32; i++){
    int pos = i*2 + prow2;
    t[pos][dcol] = v[(size_t)(p0+pos)*DIM + h*HD + dcol];
  }
  __syncthreads();
  int pos = tid & 63, dbase = tid >> 6;
  #pragma unroll
  for (int i = 0; i < 32; i++){
    int d = i*4 + dbase;
    Vt[((size_t)h*HD + d)*SEQN + p0 + pos] = f2bf(t[pos][d]);
  }
}

// ---------------- IP attention (MFMA): 2048 q x 64 keys per head, exact softmax ----------------
__global__ __launch_bounds__(256) void ip_attn_m(const float* __restrict__ qb,
                                                 const unsigned short* __restrict__ ipk_bf,
                                                 const unsigned short* __restrict__ ipv_t,
                                                 float* __restrict__ out){
  __shared__ unsigned short Ks[64*HD];
  __shared__ unsigned short Vs[HD*64];
  __shared__ unsigned short Ps[4][16*64];
  int tid = threadIdx.x, lane = tid & 63, w = tid >> 6;
  int l15 = lane & 15, l16 = lane >> 4;
  int h = blockIdx.y;
  int q0 = blockIdx.x*64 + w*16;
  const unsigned short* Kh = ipk_bf + (size_t)h*NIPN*HD;
  const unsigned short* Vh = ipv_t + (size_t)h*HD*NIPN;

  #pragma unroll
  for (int i = 0; i < 4; i++){
    int p = i*256 + tid;
    int row = p >> 4, cc = p & 15;
    int gc = cc ^ (row & 7);
    GL16(Kh + (size_t)row*HD + gc*8, Ks + p*8);
  }
  #pragma unroll
  for (int i = 0; i < 4; i++){
    int p = i*256 + tid;
    int row = p >> 3, cc = p & 7;
    int gc = cc ^ (row & 7);
    GL16(Vh + (size_t)row*64 + gc*8, Vs + p*8);
  }

  // q fragments from fp32 qb (original_query = pre-norm q, rows < 2048)
  s8v qf[4];
  #pragma unroll
  for (int kf = 0; kf < 4; kf++){
    const float* qp = qb + (size_t)(q0 + l15)*DIM + h*HD + kf*32 + l16*8;
    float4 a = *(const float4*)qp;
    float4 b = *(const float4*)(qp + 4);
    s8v f;
    f[0]=(short)f2bf(a.x); f[1]=(short)f2bf(a.y); f[2]=(short)f2bf(a.z); f[3]=(short)f2bf(a.w);
    f[4]=(short)f2bf(b.x); f[5]=(short)f2bf(b.y); f[6]=(short)f2bf(b.z); f[7]=(short)f2bf(b.w);
    qf[kf] = f;
  }
  __syncthreads();

  fx4 s[4] = {};
  #pragma unroll
  for (int ct = 0; ct < 4; ct++){
    #pragma unroll
    for (int kk = 0; kk < 4; kk++){
      int row = ct*16 + l15;
      int c = (kk*4 + l16) ^ (row & 7);
      s8v b = *(const s8v*)(Ks + row*HD + c*8);
      s[ct] = MFMA(qf[kk], b, s[ct]);
    }
  }
  const float SC = 0.08838834764831845f;
  float lrow[4], mx[4];
  #pragma unroll
  for (int j = 0; j < 4; j++){
    #pragma unroll
    for (int ct = 0; ct < 4; ct++) s[ct][j] *= SC;
    float v = fmaxf(fmaxf(s[0][j], s[1][j]), fmaxf(s[2][j], s[3][j]));
    #pragma unroll
    for (int o2 = 1; o2 < 16; o2 <<= 1) v = fmaxf(v, __shfl_xor(v, o2));
    mx[j] = v;
    float sum = 0.f;
    #pragma unroll
    for (int ct = 0; ct < 4; ct++){
      float p = __expf(s[ct][j] - v);
      s[ct][j] = p;
      sum += p;
    }
    #pragma unroll
    for (int o2 = 1; o2 < 16; o2 <<= 1) sum += __shfl_xor(sum, o2);
    lrow[j] = sum;
  }

  // P -> bf16 via swizzled per-wave LDS
  #pragma unroll
  for (int ct = 0; ct < 4; ct++)
    #pragma unroll
    for (int j = 0; j < 4; j++){
      int row = l16*4 + j;
      int cidx = ct*16 + l15;
      Ps[w][row*64 + (((cidx>>3) ^ (row&7))<<3) + (cidx&7)] = f2bf(s[ct][j]);
    }
  asm volatile("s_waitcnt lgkmcnt(0)" ::: "memory");
  s8v pa[2];
  #pragma unroll
  for (int kk = 0; kk < 2; kk++){
    int c = (kk*4 + l16) ^ (l15 & 7);
    pa[kk] = *(const s8v*)(&Ps[w][l15*64 + c*8]);
  }
  fx4 o[8] = {};
  #pragma unroll
  for (int nt = 0; nt < 8; nt++){
    #pragma unroll
    for (int kk = 0; kk < 2; kk++){
      int row = nt*16 + l15;
      int c = (kk*4 + l16) ^ (row & 7);
      s8v bv = *(const s8v*)(Vs + row*64 + c*8);
      o[nt] = MFMA(pa[kk], bv, o[nt]);
    }
  }
  #pragma unroll
  for (int nt = 0; nt < 8; nt++)
    #pragma unroll
    for (int j = 0; j < 4; j++){
      int row = q0 + l16*4 + j;
      int d = nt*16 + l15;
      out[(size_t)row*DIM + h*HD + d] = o[nt][j] / lrow[j];
    }
}

// ---------------- main flash attention: 2048 q rows x 3072 keys, no mask ----------------
#define QB 64
#define KVB 64
__global__ __launch_bounds__(256) void flash_attn(const unsigned short* __restrict__ Qn,
                                                  const unsigned short* __restrict__ Kn,
                                                  const unsigned short* __restrict__ Vt,
                                                  float* __restrict__ out){
  __shared__ unsigned short Ks[KVB*HD];
  __shared__ unsigned short Vs[HD*KVB];
  __shared__ unsigned short Ps[4][16*KVB];
  int tid = threadIdx.x, lane = tid & 63, w = tid >> 6;
  int l15 = lane & 15, l16 = lane >> 4;
  int h = blockIdx.y;
  int q0 = blockIdx.x*QB + w*16;
  const unsigned short* Qh = Qn + (size_t)h*BLK*HD;
  const unsigned short* Kh = Kn + (size_t)h*SEQN*HD;
  const unsigned short* Vh = Vt + (size_t)h*HD*SEQN;

  s8v qf[4];
  #pragma unroll
  for (int kf = 0; kf < 4; kf++)
    qf[kf] = *(const s8v*)(Qh + (size_t)(q0 + l15)*HD + kf*32 + l16*8);

  fx4 o[8] = {};
  float mrow[4], lrow[4];
  #pragma unroll
  for (int j = 0; j < 4; j++){ mrow[j] = -1e30f; lrow[j] = 0.f; }

  for (int kv0 = 0; kv0 < SEQN; kv0 += KVB){
    #pragma unroll
    for (int i = 0; i < 4; i++){
      int p = i*256 + tid;
      int row = p >> 4, cc = p & 15;
      int gc = cc ^ (row & 7);
      GL16(Kh + (size_t)(kv0+row)*HD + gc*8, Ks + p*8);
    }
    #pragma unroll
    for (int i = 0; i < 4; i++){
      int p = i*256 + tid;
      int row = p >> 3, cc = p & 7;
      int gc = cc ^ (row & 7);
      GL16(Vh + (size_t)row*SEQN + kv0 + gc*8, Vs + p*8);
    }
    __syncthreads();

    fx4 s[4] = {};
    #pragma unroll
    for (int ct = 0; ct < 4; ct++){
      #pragma unroll
      for (int kk = 0; kk < 4; kk++){
        int row = ct*16 + l15;
        int c = (kk*4 + l16) ^ (row & 7);
        s8v b = *(const s8v*)(Ks + row*HD + c*8);
        s[ct] = MFMA(qf[kk], b, s[ct]);
      }
    }
    const float SC = 0.08838834764831845f;
    #pragma unroll
    for (int ct = 0; ct < 4; ct++)
      #pragma unroll
      for (int j = 0; j < 4; j++) s[ct][j] *= SC;

    float mnew[4], alpha[4], rssum[4];
    #pragma unroll
    for (int j = 0; j < 4; j++){
      float v = fmaxf(fmaxf(s[0][j], s[1][j]), fmaxf(s[2][j], s[3][j]));
      #pragma unroll
      for (int o2 = 1; o2 < 16; o2 <<= 1) v = fmaxf(v, __shfl_xor(v, o2));
      mnew[j] = fmaxf(mrow[j], v);
      alpha[j] = __expf(mrow[j] - mnew[j]);
      mrow[j] = mnew[j];
      rssum[j] = 0.f;
    }
    #pragma unroll
    for (int ct = 0; ct < 4; ct++)
      #pragma unroll
      for (int j = 0; j < 4; j++){
        float p = __expf(s[ct][j] - mnew[j]);
        s[ct][j] = p;
        rssum[j] += p;
      }
    #pragma unroll
    for (int j = 0; j < 4; j++){
      #pragma unroll
      for (int o2 = 1; o2 < 16; o2 <<= 1) rssum[j] += __shfl_xor(rssum[j], o2);
      lrow[j] = lrow[j]*alpha[j] + rssum[j];
    }
    #pragma unroll
    for (int nt = 0; nt < 8; nt++)
      #pragma unroll
      for (int j = 0; j < 4; j++) o[nt][j] *= alpha[j];

    // write P to per-wave swizzled LDS
    #pragma unroll
    for (int ct = 0; ct < 4; ct++)
      #pragma unroll
      for (int j = 0; j < 4; j++){
        int row = l16*4 + j;
        int cidx = ct*16 + l15;
        Ps[w][row*64 + (((cidx>>3) ^ (row&7))<<3) + (cidx&7)] = f2bf(s[ct][j]);
      }
    asm volatile("s_waitcnt lgkmcnt(0)" ::: "memory");
    s8v pa[2];
    #pragma unroll
    for (int kk = 0; kk < 2; kk++){
      int c = (kk*4 + l16) ^ (l15 & 7);
      pa[kk] = *(const s8v*)(&Ps[w][l15*64 + c*8]);
    }
    #pragma unroll
    for (int nt = 0; nt < 8; nt++){
      #pragma unroll
      for (int kk = 0; kk < 2; kk++){
        int row = nt*16 + l15;
        int c = (kk*4 + l16) ^ (row & 7);
        s8v bv = *(const s8v*)(Vs + row*KVB + c*8);
        o[nt] = MFMA(pa[kk], bv, o[nt]);
      }
    }
    __syncthreads();
  }
  #pragma unroll
  for (int nt = 0; nt < 8; nt++)
    #pragma unroll
    for (int j = 0; j < 4; j++){
      int row = q0 + l16*4 + j;
      int d = nt*16 + l15;
      float v = o[nt][j] / lrow[j];
      float* p = out + (size_t)row*DIM + h*HD + d;
      *p += v;
    }
}

extern "C" void kernel_launch(void* const* d_in, const int* in_sizes, int n_in,
                              void* d_out, int out_size, void* d_ws, size_t ws_size,
                              hipStream_t stream){
  (void)in_sizes; (void)n_in; (void)out_size;
  const float* hs       = (const float*)d_in[0];
  const float* image_emb= (const float*)d_in[1];
  const float* rope_cos = (const float*)d_in[2];
  const float* rope_sin = (const float*)d_in[3];
  const float* wq = (const float*)d_in[4];
  const float* bq = (const float*)d_in[5];
  const float* wk = (const float*)d_in[6];
  const float* bk = (const float*)d_in[7];
  const float* wv = (const float*)d_in[8];
  const float* bv = (const float*)d_in[9];
  const float* norm_q_w = (const float*)d_in[10];
  const float* norm_k_w = (const float*)d_in[11];
  const float* q_down = (const float*)d_in[12];
  const float* q_up   = (const float*)d_in[13];
  const float* k_down = (const float*)d_in[14];
  const float* k_up   = (const float*)d_in[15];
  const float* v_down = (const float*)d_in[16];
  const float* v_up   = (const float*)d_in[17];
  const float* wk_ip  = (const float*)d_in[18];
  const float* wv_ip  = (const float*)d_in[19];
  float* out = (float*)d_out;

  char* ws = (char*)d_ws;
  size_t off = 0;
  auto alloc = [&](size_t bytes){ void* p = ws + off; off += (bytes + 255) & ~(size_t)255; return p; };
  unsigned short* hs_bf = (unsigned short*)alloc((size_t)SEQN*DIM*2);
  unsigned short* w_bf  = (unsigned short*)alloc((size_t)DIM*DIM*2);
  unsigned short* ie_bf = (unsigned short*)alloc((size_t)NIPN*DIM*2);
  float* qb = (float*)alloc((size_t)SEQN*DIM*4);
  float* kb = (float*)alloc((size_t)SEQN*DIM*4);
  float* vb = (float*)alloc((size_t)SEQN*DIM*4);
  float* ipk_pre = (float*)alloc((size_t)NIPN*DIM*4);
  float* ipv_pre = (float*)alloc((size_t)NIPN*DIM*4);
  unsigned short* ipk_bf = (unsigned short*)alloc((size_t)HEADS*NIPN*HD*2);
  unsigned short* ipv_t  = (unsigned short*)alloc((size_t)HEADS*HD*NIPN*2);
  unsigned short* dwn_bf[3];
  unsigned short* upw_bf[3];
  for (int i = 0; i < 3; i++) dwn_bf[i] = (unsigned short*)alloc((size_t)RANKN*DIM*2);
  for (int i = 0; i < 3; i++) upw_bf[i] = (unsigned short*)alloc((size_t)DIM*RANKN*2);
  unsigned short* downb_bf = (unsigned short*)alloc((size_t)3*CONDN*RANKN*2);
  unsigned short* Qn = (unsigned short*)alloc((size_t)HEADS*BLK*HD*2);
  unsigned short* Kn = (unsigned short*)alloc((size_t)HEADS*SEQN*HD*2);
  unsigned short* Vt = (unsigned short*)alloc((size_t)HEADS*HD*SEQN*2);
  if (off > ws_size) return;  // workspace too small -> leave output poisoned (visible failure)

  int n4;
  n4 = SEQN*DIM/4;
  cvt_f32_bf16<<<(n4+255)/256, 256, 0, stream>>>(hs, hs_bf, n4);
  n4 = NIPN*DIM/4;
  cvt_f32_bf16<<<(n4+255)/256, 256, 0, stream>>>(image_emb, ie_bf, n4);

  dim3 gfull(DIM/BN, SEQN/BM);
  dim3 gip(DIM/BN, 1);
  n4 = DIM*DIM/4;
  cvt_f32_bf16<<<(n4+255)/256, 256, 0, stream>>>(wq, w_bf, n4);
  gemm_bf16<<<gfull, 256, 0, stream>>>(hs_bf, w_bf, qb, bq, SEQN);
  cvt_f32_bf16<<<(n4+255)/256, 256, 0, stream>>>(wk, w_bf, n4);
  gemm_bf16<<<gfull, 256, 0, stream>>>(hs_bf, w_bf, kb, bk, SEQN);
  cvt_f32_bf16<<<(n4+255)/256, 256, 0, stream>>>(wv, w_bf, n4);
  gemm_bf16<<<gfull, 256, 0, stream>>>(hs_bf, w_bf, vb, bv, SEQN);
  cvt_f32_bf16<<<(n4+255)/256, 256, 0, stream>>>(wk_ip, w_bf, n4);
  gemm_bf16<<<gip, 256, 0, stream>>>(ie_bf, w_bf, ipk_pre, nullptr, NIPN);
  cvt_f32_bf16<<<(n4+255)/256, 256, 0, stream>>>(wv_ip, w_bf, n4);
  gemm_bf16<<<gip, 256, 0, stream>>>(ie_bf, w_bf, ipv_pre, nullptr, NIPN);

  // LoRA path (MFMA)
  n4 = RANKN*DIM/4;
  cvt_f32_bf16<<<(n4+255)/256, 256, 0, stream>>>(q_down, dwn_bf[0], n4);
  cvt_f32_bf16<<<(n4+255)/256, 256, 0, stream>>>(k_down, dwn_bf[1], n4);
  cvt_f32_bf16<<<(n4+255)/256, 256, 0, stream>>>(v_down, dwn_bf[2], n4);
  cvt_f32_bf16<<<(n4+255)/256, 256, 0, stream>>>(q_up, upw_bf[0], n4);
  cvt_f32_bf16<<<(n4+255)/256, 256, 0, stream>>>(k_up, upw_bf[1], n4);
  cvt_f32_bf16<<<(n4+255)/256, 256, 0, stream>>>(v_up, upw_bf[2], n4);
  lora_down_g<<<dim3(1, CONDN/128, 3), 256, 0, stream>>>(hs_bf + (size_t)BLK*DIM,
      dwn_bf[0], dwn_bf[1], dwn_bf[2], downb_bf);
  lora_up_g<<<dim3(DIM/128, CONDN/128, 3), 256, 0, stream>>>(downb_bf,
      upw_bf[0], upw_bf[1], upw_bf[2], qb, kb, vb);

  ipk_norm_bf<<<(NIPN*HEADS)/4, 256, 0, stream>>>(ipk_pre, ipk_bf);
  ipv_transpose<<<HEADS, 256, 0, stream>>>(ipv_pre, ipv_t);
  norm_rope<<<(BLK*HEADS)/4, 256, 0, stream>>>(qb, Qn, norm_q_w, rope_cos, rope_sin, BLK);
  norm_rope<<<(SEQN*HEADS)/4, 256, 0, stream>>>(kb, Kn, norm_k_w, rope_cos, rope_sin, SEQN);
  v_transpose<<<dim3(SEQN/64, HEADS), 256, 0, stream>>>(vb, Vt);

  ip_attn_m<<<dim3(BLK/64, HEADS), 256, 0, stream>>>(qb, ipk_bf, ipv_t, out);
  flash_attn<<<dim3(BLK/QB, HEADS), 256, 0, stream>>>(Qn, Kn, Vt, out);
}